// Round 1
// baseline (713.513 us; speedup 1.0000x reference)
//
#include <hip/hip_runtime.h>
#include <hip/hip_bf16.h>

// Problem constants (B=2,H=16,S=2048,D=64)
#define BDIM 2
#define HDIM 16
#define SDIM 2048
#define DDIM 64
#define KT   64                 // keys per chunk
#define QW   32                 // q rows per wave
#define NWAVE 4
#define QB   (QW * NWAVE)       // 128 q rows per block
#define NCHUNK (SDIM / KT)      // 32

typedef __attribute__((ext_vector_type(8))) short   short8;
typedef __attribute__((ext_vector_type(8))) __bf16  bf16x8;
typedef __attribute__((ext_vector_type(4))) float   floatx4;

#if __has_builtin(__builtin_amdgcn_exp2f)
#define EXP2(x) __builtin_amdgcn_exp2f(x)
#else
#define EXP2(x) exp2f(x)
#endif

// RNE float->bf16 (inputs are finite; no NaN path needed)
static __device__ __forceinline__ unsigned short f2bf(float f) {
  unsigned int u = __builtin_bit_cast(unsigned int, f);
  u += 0x7fffu + ((u >> 16) & 1u);
  return (unsigned short)(u >> 16);
}

static __device__ __forceinline__ floatx4 mfma16(short8 a, short8 b, floatx4 c) {
  return __builtin_amdgcn_mfma_f32_16x16x32_bf16(
      __builtin_bit_cast(bf16x8, a), __builtin_bit_cast(bf16x8, b), c, 0, 0, 0);
}

// ---------- prepack: fp32 -> bf16 (K) ----------
__global__ __launch_bounds__(256) void k_cvt_bf16(const float* __restrict__ src,
                                                  unsigned short* __restrict__ dst) {
  int i = blockIdx.x * 256 + threadIdx.x;          // one float4 per thread
  float4 v = ((const float4*)src)[i];
  ushort4 o;
  o.x = f2bf(v.x); o.y = f2bf(v.y); o.z = f2bf(v.z); o.w = f2bf(v.w);
  ((ushort4*)dst)[i] = o;
}

// ---------- prepack: V -> V^T bf16 ([bh][d][k]) ----------
__global__ __launch_bounds__(256) void k_vt(const float* __restrict__ V,
                                            unsigned short* __restrict__ Vt) {
  __shared__ float t[64][65];
  const int kb = blockIdx.x * 64, bh = blockIdx.y, tid = threadIdx.x;
  const float* src = V + ((size_t)bh * SDIM + kb) * DDIM;
#pragma unroll
  for (int i = 0; i < 16; i++) { int e = i * 256 + tid; t[e >> 6][e & 63] = src[e]; }
  __syncthreads();
  unsigned short* dst = Vt + (size_t)bh * DDIM * SDIM + kb;
#pragma unroll
  for (int i = 0; i < 16; i++) {
    int e = i * 256 + tid; int d = e >> 6, k = e & 63;
    dst[(size_t)d * SDIM + k] = f2bf(t[k][d]);
  }
}

// ---------- prepack: mask int32 -> bit-packed u64 ----------
__global__ __launch_bounds__(256) void k_maskbits(const int* __restrict__ mask,
                                                  unsigned long long* __restrict__ Mb) {
  const int w = threadIdx.x >> 6, lane = threadIdx.x & 63;
  const int task = blockIdx.x * 4 + w;             // (b*2048+q)*32 + c
  int v = mask[(size_t)task * 64 + lane];
  unsigned long long bm = __ballot(v != 0);
  if (lane == 0) Mb[task] = bm;
}

// ---------- main fused attention ----------
__global__ __launch_bounds__(256, 2) void k_attn(
    const float* __restrict__ Qg, const unsigned short* __restrict__ Kb,
    const unsigned short* __restrict__ Vt, const unsigned long long* __restrict__ Mb,
    float* __restrict__ Og, float* __restrict__ Pg) {
  // LDS: region A (16KB): Q tile, later per-wave P staging; B (8KB): K chunk; C (8KB): V^T chunk
  __shared__ unsigned short smem[16384];
  unsigned short* A   = smem;
  unsigned short* Ksm = smem + 8192;
  unsigned short* Vsm = smem + 12288;

  const int tid = threadIdx.x;
  const int w = tid >> 6, lane = tid & 63;
  const int quad = lane >> 4, l15 = lane & 15;
  const int qt = blockIdx.x, bh = blockIdx.y, b = bh >> 4;
  const int q0 = qt * QB;

  // stage Q tile fp32 -> bf16 into A
  {
    const float* qptr = Qg + ((size_t)bh * SDIM + q0) * DDIM;
#pragma unroll
    for (int i = 0; i < 32; i++) { int e = i * 256 + tid; A[e] = f2bf(qptr[e]); }
  }
  __syncthreads();

  // Q a-frags: A[m=l15][k=quad*8+j] per 16x32 tile
  short8 aq[2][2];
#pragma unroll
  for (int mt = 0; mt < 2; mt++)
#pragma unroll
    for (int dh = 0; dh < 2; dh++)
      aq[mt][dh] = *(const short8*)&A[(w * QW + mt * 16 + l15) * DDIM + dh * 32 + quad * 8];

  const float SCL2 = 0.125f * 1.44269504088896f;   // scale * log2(e)
  const float NEG2 = -1.442695e9f;                 // -1e9 * log2(e)

  float mrun[2][4], lrun[2][4];
  int mrow_idx[2][4], prow[2][4];
#pragma unroll
  for (int mt = 0; mt < 2; mt++)
#pragma unroll
    for (int r = 0; r < 4; r++) {
      mrun[mt][r] = -3.0e38f; lrun[mt][r] = 0.f;
      int rq = q0 + w * QW + mt * 16 + quad * 4 + r;
      mrow_idx[mt][r] = (b * SDIM + rq) * NCHUNK;
      prow[mt][r] = (bh * SDIM + rq);
    }

  const unsigned short* kbase = Kb + (size_t)bh * SDIM * DDIM;
  const unsigned short* vtb   = Vt + (size_t)bh * DDIM * SDIM;

  // ================= PASS 1: row stats =================
  for (int c = 0; c < NCHUNK; c++) {
    __syncthreads();
    {
      const short8* kp = (const short8*)(kbase + (size_t)(c * KT) * DDIM);
      short8* kd = (short8*)Ksm;
#pragma unroll
      for (int i = 0; i < 2; i++) { int e = i * 256 + tid; kd[e] = kp[e]; }
    }
    __syncthreads();
    short8 bk[4][2];
#pragma unroll
    for (int nt = 0; nt < 4; nt++)
#pragma unroll
      for (int dh = 0; dh < 2; dh++)
        bk[nt][dh] = *(const short8*)&Ksm[(nt * 16 + l15) * DDIM + dh * 32 + quad * 8];
#pragma unroll
    for (int mt = 0; mt < 2; mt++) {
      floatx4 acc[4];
#pragma unroll
      for (int nt = 0; nt < 4; nt++) {
        floatx4 z = {0.f, 0.f, 0.f, 0.f};
        z = mfma16(aq[mt][0], bk[nt][0], z);
        acc[nt] = mfma16(aq[mt][1], bk[nt][1], z);
      }
#pragma unroll
      for (int r = 0; r < 4; r++) {
        unsigned long long mb = Mb[mrow_idx[mt][r] + c];
        float v[4];
#pragma unroll
        for (int nt = 0; nt < 4; nt++) {
          int kloc = nt * 16 + l15;
          bool keep = (mb >> kloc) & 1ull;
          v[nt] = keep ? acc[nt][r] * SCL2 : NEG2;
        }
        float cmax = fmaxf(fmaxf(v[0], v[1]), fmaxf(v[2], v[3]));
        float mnew = fmaxf(mrun[mt][r], cmax);
        float s = EXP2(v[0] - mnew) + EXP2(v[1] - mnew) +
                  EXP2(v[2] - mnew) + EXP2(v[3] - mnew);
        lrun[mt][r] = lrun[mt][r] * EXP2(mrun[mt][r] - mnew) + s;
        mrun[mt][r] = mnew;
      }
    }
  }

  // merge per-lane stats across the 16-lane (column) groups
  float mfin[2][4], linv[2][4];
#pragma unroll
  for (int mt = 0; mt < 2; mt++)
#pragma unroll
    for (int r = 0; r < 4; r++) {
      float m = mrun[mt][r], l = lrun[mt][r];
#pragma unroll
      for (int off = 1; off < 16; off <<= 1) {
        float om = __shfl_xor(m, off, 64);
        float ol = __shfl_xor(l, off, 64);
        float mn = fmaxf(m, om);
        l = l * EXP2(m - mn) + ol * EXP2(om - mn);
        m = mn;
      }
      mfin[mt][r] = m;
      linv[mt][r] = 1.0f / l;
    }

  // ================= PASS 2: write p, accumulate O =================
  floatx4 oacc[2][4];
#pragma unroll
  for (int mt = 0; mt < 2; mt++)
#pragma unroll
    for (int dt = 0; dt < 4; dt++) oacc[mt][dt] = (floatx4){0.f, 0.f, 0.f, 0.f};

  for (int c = 0; c < NCHUNK; c++) {
    __syncthreads();
    {
      const short8* kp = (const short8*)(kbase + (size_t)(c * KT) * DDIM);
      short8* kd = (short8*)Ksm;
#pragma unroll
      for (int i = 0; i < 2; i++) { int e = i * 256 + tid; kd[e] = kp[e]; }
      short8* vd = (short8*)Vsm;
#pragma unroll
      for (int i = 0; i < 2; i++) {
        int e = i * 256 + tid;                     // 0..511: d = e>>3, 8x short8 per row
        int d = e >> 3, o8 = e & 7;
        vd[e] = *(const short8*)&vtb[(size_t)d * SDIM + c * KT + o8 * 8];
      }
    }
    __syncthreads();
    short8 bk[4][2];
#pragma unroll
    for (int nt = 0; nt < 4; nt++)
#pragma unroll
      for (int dh = 0; dh < 2; dh++)
        bk[nt][dh] = *(const short8*)&Ksm[(nt * 16 + l15) * DDIM + dh * 32 + quad * 8];
#pragma unroll
    for (int mt = 0; mt < 2; mt++) {
      floatx4 acc[4];
#pragma unroll
      for (int nt = 0; nt < 4; nt++) {
        floatx4 z = {0.f, 0.f, 0.f, 0.f};
        z = mfma16(aq[mt][0], bk[nt][0], z);
        acc[nt] = mfma16(aq[mt][1], bk[nt][1], z);
      }
#pragma unroll
      for (int r = 0; r < 4; r++) {
        unsigned long long mb = Mb[mrow_idx[mt][r] + c];
        float m = mfin[mt][r], li = linv[mt][r];
        int pidx = prow[mt][r] * SDIM + c * KT + l15;
        int arow = w * 2048 + (mt * 16 + quad * 4 + r) * KT + l15;
#pragma unroll
        for (int nt = 0; nt < 4; nt++) {
          int kloc = nt * 16 + l15;
          bool keep = (mb >> kloc) & 1ull;
          float vv = keep ? acc[nt][r] * SCL2 : NEG2;
          float p = EXP2(vv - m) * li;
          __builtin_nontemporal_store(p, &Pg[pidx + nt * 16]);
          A[arow + nt * 16] = f2bf(p);             // per-wave P staging (C-layout -> LDS)
        }
      }
    }
    // own-wave LDS writes must complete before cross-lane reads
    asm volatile("s_waitcnt lgkmcnt(0)" ::: "memory");
    short8 bv[4][2];
#pragma unroll
    for (int dt = 0; dt < 4; dt++)
#pragma unroll
      for (int kk = 0; kk < 2; kk++)
        bv[dt][kk] = *(const short8*)&Vsm[(dt * 16 + l15) * KT + kk * 32 + quad * 8];
#pragma unroll
    for (int mt = 0; mt < 2; mt++) {
      short8 ap0 = *(const short8*)&A[w * 2048 + (mt * 16 + l15) * KT + quad * 8];
      short8 ap1 = *(const short8*)&A[w * 2048 + (mt * 16 + l15) * KT + 32 + quad * 8];
#pragma unroll
      for (int dt = 0; dt < 4; dt++) {
        oacc[mt][dt] = mfma16(ap0, bv[dt][0], oacc[mt][dt]);
        oacc[mt][dt] = mfma16(ap1, bv[dt][1], oacc[mt][dt]);
      }
    }
  }

  // epilogue: O (C-layout: row=quad*4+r, col=l15)
#pragma unroll
  for (int mt = 0; mt < 2; mt++)
#pragma unroll
    for (int dt = 0; dt < 4; dt++)
#pragma unroll
      for (int r = 0; r < 4; r++) {
        int rq = q0 + w * QW + mt * 16 + quad * 4 + r;
        Og[(bh * SDIM + rq) * DDIM + dt * 16 + l15] = oacc[mt][dt][r];
      }
}

extern "C" void kernel_launch(void* const* d_in, const int* in_sizes, int n_in,
                              void* d_out, int out_size, void* d_ws, size_t ws_size,
                              hipStream_t stream) {
  const float* Q = (const float*)d_in[0];
  const float* K = (const float*)d_in[1];
  const float* V = (const float*)d_in[2];
  const int* mask = (const int*)d_in[3];

  float* out = (float*)d_out;
  float* p = out + (size_t)BDIM * HDIM * SDIM * DDIM;

  const size_t nqkv = (size_t)BDIM * HDIM * SDIM * DDIM;   // 4.19M elems
  unsigned short* Kb = (unsigned short*)d_ws;              // 8.39 MB
  unsigned short* Vt = Kb + nqkv;                          // 8.39 MB
  unsigned long long* Mb = (unsigned long long*)(Vt + nqkv); // 1.05 MB

  k_cvt_bf16<<<(int)(nqkv / 4 / 256), 256, 0, stream>>>(K, Kb);
  k_vt<<<dim3(SDIM / 64, BDIM * HDIM), 256, 0, stream>>>(V, Vt);
  k_maskbits<<<(BDIM * SDIM * (SDIM / 64)) / 4, 256, 0, stream>>>(mask, Mb);
  k_attn<<<dim3(SDIM / QB, BDIM * HDIM), 256, 0, stream>>>(Q, Kb, Vt, Mb, out, p);
}